// Round 6
// baseline (597.682 us; speedup 1.0000x reference)
//
#include <hip/hip_runtime.h>
#include <stdint.h>

// ---------------------------------------------------------------------------
// Qwen2 MoE sparse block, MI355X/gfx950.  FP32 I/O, bf16 MFMA internally.
// T=2048, D=2048, E=8, F=1408, top-2.  Sparse dispatch (~71 GFLOP vs 283).
// Round 6: BK=64 K-loops (half the barrier drains, split-half LDS for gld16
// lane-contiguity), finalize fused into router (last-block-done), gemm2
// accumulates straight into fp32 out via atomicAdd (no Y buffer, no combine).
// 7 dispatches total (was 9).
// ---------------------------------------------------------------------------

#define TT 2048
#define DD 2048
#define FF 1408
#define NE 8
#define HROWS 5120          // >= sum of per-expert counts padded to 128 (<=5112)

typedef float f32x4 __attribute__((ext_vector_type(4)));
typedef short bf16x8 __attribute__((ext_vector_type(8)));

__device__ __forceinline__ unsigned short f2bf(float f) {
    unsigned int x = __float_as_uint(f);
    return (unsigned short)((x + 0x7fffu + ((x >> 16) & 1u)) >> 16);
}
__device__ __forceinline__ void gld16(const void* g, void* l) {
    __builtin_amdgcn_global_load_lds((const __attribute__((address_space(1))) void*)g,
                                     (__attribute__((address_space(3))) void*)l, 16, 0, 0);
}

// ---------------------------------------------------------------------------
// Register-blocklet transpose + fp32->bf16.  128x128 src tile per block,
// 4 waves in 2x2 of 64x64, thread = 8x8 blocklet.  No LDS.
// ---------------------------------------------------------------------------
__device__ __forceinline__ void treg(const float* __restrict__ src,
                                     unsigned short* __restrict__ dst,
                                     int R, int C, int r0, int c0) {
    const int lane = threadIdx.x & 63, w = threadIdx.x >> 6;
    const int bi = lane >> 3, bj = lane & 7;
    const int sr = r0 + (w & 1) * 64 + bi * 8;
    const int sc = c0 + (w >> 1) * 64 + bj * 8;
    float4 fa[8], fb[8];
#pragma unroll
    for (int k = 0; k < 8; ++k) {
        const float* p = src + (size_t)(sr + k) * C + sc;
        fa[k] = ((const float4*)p)[0];
        fb[k] = ((const float4*)p)[1];
    }
#pragma unroll
    for (int k = 0; k < 8; ++k) {
        uint4 ov; unsigned short* po = (unsigned short*)&ov;
#pragma unroll
        for (int l = 0; l < 8; ++l) {
            float v = (k < 4) ? ((const float*)&fa[l])[k]
                              : ((const float*)&fb[l])[k - 4];
            po[l] = f2bf(v);
        }
        *(uint4*)&dst[(size_t)(sc + k) * R + sr] = ov;
    }
}

// w_gate/w_up [E][D][F] fp32 -> [E][F][D] bf16.  grid (11, 16, 16)
__global__ void transpose_gu_kernel(const float* __restrict__ wg,
                                    const float* __restrict__ wu,
                                    unsigned short* __restrict__ WgT,
                                    unsigned short* __restrict__ WuT) {
    const int z = blockIdx.z;
    const float* src; unsigned short* dst;
    if (z < 8) { src = wg + (size_t)z * DD * FF;       dst = WgT + (size_t)z * FF * DD; }
    else       { src = wu + (size_t)(z - 8) * DD * FF; dst = WuT + (size_t)(z - 8) * FF * DD; }
    treg(src, dst, DD, FF, blockIdx.y * 128, blockIdx.x * 128);
}

// w_down [E][F][D] fp32 -> [E][D][F] bf16.  grid (16, 11, 8)
__global__ void transpose_d_kernel(const float* __restrict__ wd,
                                   unsigned short* __restrict__ WdT) {
    const int z = blockIdx.z;
    treg(wd + (size_t)z * FF * DD, WdT + (size_t)z * DD * FF,
         FF, DD, blockIdx.y * 128, blockIdx.x * 128);
}

// ---------------------------------------------------------------------------
// Router (wave/token, exact fp32) + fused X->bf16 emit + fused finalize
// (last block pads lists to x128 and prefix-sums bases).
// ---------------------------------------------------------------------------
__global__ void router_kernel(const float* __restrict__ x,
                              const float* __restrict__ gw,
                              int* __restrict__ cnt,        // [NE], cnt[NE]=done
                              int* __restrict__ tok,
                              float* __restrict__ wtv,
                              int* __restrict__ tdx,        // dest token index
                              unsigned short* __restrict__ xb,
                              int* __restrict__ basep,
                              int* __restrict__ cntpad) {
    __shared__ int s_last;
    __shared__ int sc[NE], sp[NE];

    const int wv = threadIdx.x >> 6, lane = threadIdx.x & 63;
    const int t = blockIdx.x * 4 + wv;
    float acc[NE];
#pragma unroll
    for (int e = 0; e < NE; ++e) acc[e] = 0.f;
    const float* xr = x + (size_t)t * DD;
    unsigned short* xbr = xb + (size_t)t * DD;
#pragma unroll
    for (int it = 0; it < DD / 256; ++it) {
        const int j = it * 256 + lane * 4;
        float4 xv = *(const float4*)(xr + j);
        short4 o;
        o.x = (short)f2bf(xv.x); o.y = (short)f2bf(xv.y);
        o.z = (short)f2bf(xv.z); o.w = (short)f2bf(xv.w);
        *(short4*)(xbr + j) = o;
#pragma unroll
        for (int e = 0; e < NE; ++e) {
            float4 g = *(const float4*)(gw + e * DD + j);
            acc[e] += xv.x * g.x + xv.y * g.y + xv.z * g.z + xv.w * g.w;
        }
    }
#pragma unroll
    for (int e = 0; e < NE; ++e) {
        float v = acc[e];
        v += __shfl_xor(v, 32); v += __shfl_xor(v, 16); v += __shfl_xor(v, 8);
        v += __shfl_xor(v, 4);  v += __shfl_xor(v, 2);  v += __shfl_xor(v, 1);
        acc[e] = v;
    }
    if (lane == 0) {
        float mx = acc[0];
#pragma unroll
        for (int e = 1; e < NE; ++e) mx = fmaxf(mx, acc[e]);
        float p[NE], s = 0.f;
#pragma unroll
        for (int e = 0; e < NE; ++e) { p[e] = __expf(acc[e] - mx); s += p[e]; }
        int i0 = 0;
#pragma unroll
        for (int e = 1; e < NE; ++e) if (p[e] > p[i0]) i0 = e;
        int i1 = (i0 == 0) ? 1 : 0;
#pragma unroll
        for (int e = 0; e < NE; ++e) if (e != i0 && p[e] > p[i1]) i1 = e;
        float inv = 1.f / s;
        int p0 = atomicAdd(&cnt[i0], 1);
        tok[i0 * TT + p0] = t; wtv[i0 * TT + p0] = p[i0] * inv; tdx[i0 * TT + p0] = t;
        int p1 = atomicAdd(&cnt[i1], 1);
        tok[i1 * TT + p1] = t; wtv[i1 * TT + p1] = p[i1] * inv; tdx[i1 * TT + p1] = t;
    }

    // ---- fused finalize: last block pads + prefix-sums ----
    __syncthreads();
    if (threadIdx.x == 0) {
        __threadfence();
        int d = atomicAdd(&cnt[NE], 1);
        s_last = (d == (TT / 4) - 1) ? 1 : 0;
    }
    __syncthreads();
    if (s_last) {
        if (threadIdx.x == 0) {
            int b = 0;
            for (int e = 0; e < NE; ++e) {
                int c = atomicAdd(&cnt[e], 0);        // coherent read
                int pd = (c + 127) & ~127;
                basep[e] = b; cntpad[e] = pd; sc[e] = c; sp[e] = pd; b += pd;
            }
        }
        __syncthreads();
        for (int e = 0; e < NE; ++e)
            for (int i = sc[e] + (int)threadIdx.x; i < sp[e]; i += 256) {
                tok[e * TT + i] = 0; wtv[e * TT + i] = 0.f; tdx[e * TT + i] = 0;
            }
    }
}

// ---------------------------------------------------------------------------
// GEMM1 fused gate+up+silu*mul.  128M x 64N tile, BK=64 (two 32-k halves per
// barrier pair; split-half LDS keeps gld16 lane-contiguous).
// ---------------------------------------------------------------------------
__launch_bounds__(256, 2)
__global__ void gemm1_kernel(const unsigned short* __restrict__ Xb,
                             const unsigned short* __restrict__ WgT,
                             const unsigned short* __restrict__ WuT,
                             const int* __restrict__ tok,
                             const int* __restrict__ base,
                             const int* __restrict__ cntpad,
                             unsigned short* __restrict__ H) {
    __shared__ unsigned short As[2 * 128 * 32];   // [half][row][32]
    __shared__ unsigned short Bg[2 * 64 * 32];
    __shared__ unsigned short Bu[2 * 64 * 32];
    __shared__ int s_tok[128];

    const int e = blockIdx.z, rb = blockIdx.y, fb = blockIdx.x;
    const int cp = cntpad[e];
    if (rb * 128 >= cp) return;
    const int b0 = base[e];

    const int tid = threadIdx.x;
    if (tid < 128) s_tok[tid] = tok[e * TT + rb * 128 + tid];
    __syncthreads();

    const int w = tid >> 6, lane = tid & 63;
    const int r = lane & 15, q = lane >> 4;
    const int wm = w & 1, wn = w >> 1;

    const int arow = w * 32 + (lane >> 2);
    const int brow = w * 16 + (lane >> 2);
    const int koff = (lane & 3) * 8;
    const unsigned short* ga0 = Xb + (size_t)s_tok[arow] * DD + koff;
    const unsigned short* ga1 = Xb + (size_t)s_tok[arow + 16] * DD + koff;
    const size_t wb = (size_t)e * FF * DD + (size_t)(fb * 64 + brow) * DD + koff;
    const unsigned short* gg = WgT + wb;
    const unsigned short* gu = WuT + wb;
    unsigned short* la0 = As + arow * 32 + koff;   // = wave base + lane*16B
    unsigned short* la1 = la0 + 16 * 32;
    unsigned short* lg  = Bg + brow * 32 + koff;
    unsigned short* lu  = Bu + brow * 32 + koff;

    f32x4 accg[4][2] = {};
    f32x4 accu[4][2] = {};

    for (int kt = 0; kt < DD / 64; ++kt) {
        gld16(ga0, la0);           gld16(ga1, la1);
        gld16(gg,  lg);            gld16(gu,  lu);
        gld16(ga0 + 32, la0 + 4096); gld16(ga1 + 32, la1 + 4096);
        gld16(gg + 32,  lg + 2048);  gld16(gu + 32,  lu + 2048);
        ga0 += 64; ga1 += 64; gg += 64; gu += 64;
        __syncthreads();
#pragma unroll
        for (int h = 0; h < 2; ++h) {
            const unsigned short* Ah = As + h * 4096;
            const unsigned short* Gh = Bg + h * 2048;
            const unsigned short* Uh = Bu + h * 2048;
            bf16x8 af[4], gf[2], uf[2];
#pragma unroll
            for (int m = 0; m < 4; ++m)
                af[m] = *(const bf16x8*)&Ah[(wm * 64 + m * 16 + r) * 32 + q * 8];
#pragma unroll
            for (int n = 0; n < 2; ++n) {
                gf[n] = *(const bf16x8*)&Gh[(wn * 32 + n * 16 + r) * 32 + q * 8];
                uf[n] = *(const bf16x8*)&Uh[(wn * 32 + n * 16 + r) * 32 + q * 8];
            }
#pragma unroll
            for (int m = 0; m < 4; ++m)
#pragma unroll
                for (int n = 0; n < 2; ++n) {
                    accg[m][n] = __builtin_amdgcn_mfma_f32_16x16x32_bf16(af[m], gf[n], accg[m][n], 0, 0, 0);
                    accu[m][n] = __builtin_amdgcn_mfma_f32_16x16x32_bf16(af[m], uf[n], accu[m][n], 0, 0, 0);
                }
        }
        __syncthreads();
    }

    const size_t hr0 = (size_t)(b0 + rb * 128 + wm * 64);
#pragma unroll
    for (int m = 0; m < 4; ++m)
#pragma unroll
        for (int n = 0; n < 2; ++n)
#pragma unroll
            for (int rr = 0; rr < 4; ++rr) {
                float g = accg[m][n][rr], u = accu[m][n][rr];
                float h = (g / (1.f + __expf(-g))) * u;      // silu(g)*u
                int row = m * 16 + q * 4 + rr;
                int col = fb * 64 + wn * 32 + n * 16 + r;
                H[(hr0 + row) * FF + col] = f2bf(h);
            }
}

// ---------------------------------------------------------------------------
// GEMM2: out[t, d] += w * (H_row . WdT[d,:]).  128M x 64N, BK=64, direct
// fp32 atomicAdd into out (pads have w=0 -> add +-0).
// ---------------------------------------------------------------------------
__launch_bounds__(256, 2)
__global__ void gemm2_kernel(const unsigned short* __restrict__ H,
                             const unsigned short* __restrict__ WdT,
                             const float* __restrict__ wtv,
                             const int* __restrict__ tdx,
                             const int* __restrict__ base,
                             const int* __restrict__ cntpad,
                             float* __restrict__ out) {
    __shared__ unsigned short As[2 * 128 * 32];
    __shared__ unsigned short Bs[2 * 64 * 32];
    __shared__ float s_w[128];
    __shared__ int s_t[128];

    const int e = blockIdx.z, rb = blockIdx.y, db = blockIdx.x;
    const int cp = cntpad[e];
    if (rb * 128 >= cp) return;
    const int b0 = base[e];

    const int tid = threadIdx.x;
    if (tid < 128) {
        int idx = e * TT + rb * 128 + tid;
        s_w[tid] = wtv[idx]; s_t[tid] = tdx[idx];
    }
    __syncthreads();

    const int w = tid >> 6, lane = tid & 63;
    const int r = lane & 15, q = lane >> 4;
    const int wm = w & 1, wn = w >> 1;

    const int arow = w * 32 + (lane >> 2);
    const int brow = w * 16 + (lane >> 2);
    const int koff = (lane & 3) * 8;
    const unsigned short* ga0 = H + (size_t)(b0 + rb * 128 + arow) * FF + koff;
    const unsigned short* ga1 = ga0 + (size_t)16 * FF;
    const unsigned short* gb = WdT + (size_t)e * DD * FF + (size_t)(db * 64 + brow) * FF + koff;
    unsigned short* la0 = As + arow * 32 + koff;
    unsigned short* la1 = la0 + 16 * 32;
    unsigned short* lb  = Bs + brow * 32 + koff;

    f32x4 acc[4][2] = {};

    for (int kt = 0; kt < FF / 64; ++kt) {
        gld16(ga0, la0);           gld16(ga1, la1);
        gld16(gb,  lb);
        gld16(ga0 + 32, la0 + 4096); gld16(ga1 + 32, la1 + 4096);
        gld16(gb + 32,  lb + 2048);
        ga0 += 64; ga1 += 64; gb += 64;
        __syncthreads();
#pragma unroll
        for (int h = 0; h < 2; ++h) {
            const unsigned short* Ah = As + h * 4096;
            const unsigned short* Bh = Bs + h * 2048;
            bf16x8 af[4], bf[2];
#pragma unroll
            for (int m = 0; m < 4; ++m)
                af[m] = *(const bf16x8*)&Ah[(wm * 64 + m * 16 + r) * 32 + q * 8];
#pragma unroll
            for (int n = 0; n < 2; ++n)
                bf[n] = *(const bf16x8*)&Bh[(wn * 32 + n * 16 + r) * 32 + q * 8];
#pragma unroll
            for (int m = 0; m < 4; ++m)
#pragma unroll
                for (int n = 0; n < 2; ++n)
                    acc[m][n] = __builtin_amdgcn_mfma_f32_16x16x32_bf16(af[m], bf[n], acc[m][n], 0, 0, 0);
        }
        __syncthreads();
    }

#pragma unroll
    for (int m = 0; m < 4; ++m)
#pragma unroll
        for (int n = 0; n < 2; ++n)
#pragma unroll
            for (int rr = 0; rr < 4; ++rr) {
                int row = wm * 64 + m * 16 + q * 4 + rr;
                int col = db * 64 + wn * 32 + n * 16 + r;
                atomicAdd(out + (size_t)s_t[row] * DD + col, s_w[row] * acc[m][n][rr]);
            }
}

// ---------------------------------------------------------------------------
extern "C" void kernel_launch(void* const* d_in, const int* in_sizes, int n_in,
                              void* d_out, int out_size, void* d_ws, size_t ws_size,
                              hipStream_t stream) {
    const float* x      = (const float*)d_in[0];
    const float* gw     = (const float*)d_in[1];
    const float* w_gate = (const float*)d_in[2];
    const float* w_up   = (const float*)d_in[3];
    const float* w_down = (const float*)d_in[4];
    float* out = (float*)d_out;

    uint8_t* ws = (uint8_t*)d_ws;
    size_t off = 0;
    auto alloc = [&](size_t bytes) -> void* {
        void* p = ws + off;
        off = (off + bytes + 255) & ~(size_t)255;
        return p;
    };
    int*   cnt    = (int*)  alloc((NE + 1) * 4);       // cnt[NE] = done counter
    int*   basep  = (int*)  alloc(NE * 4);
    int*   cntpad = (int*)  alloc(NE * 4);
    int*   tok    = (int*)  alloc((size_t)NE * TT * 4);
    float* wtv    = (float*)alloc((size_t)NE * TT * 4);
    int*   tdx    = (int*)  alloc((size_t)NE * TT * 4);
    unsigned short* Xb  = (unsigned short*)alloc((size_t)TT * DD * 2);
    unsigned short* Hb  = (unsigned short*)alloc((size_t)HROWS * FF * 2);
    // Reused region: WgT+WuT (bf16) for gemm1, then WdT aliases WgT for gemm2.
    unsigned short* WT  = (unsigned short*)alloc((size_t)2 * NE * FF * DD * 2);
    unsigned short* WgT = WT;
    unsigned short* WuT = WT + (size_t)NE * FF * DD;
    unsigned short* WdT = WT;
    (void)ws_size; (void)in_sizes; (void)n_in; (void)out_size;

    hipMemsetAsync(cnt, 0, (NE + 1) * 4, stream);
    hipMemsetAsync(out, 0, (size_t)TT * DD * 4, stream);
    transpose_gu_kernel<<<dim3(11, 16, 16), 256, 0, stream>>>(w_gate, w_up, WgT, WuT);
    router_kernel<<<dim3(TT / 4), 256, 0, stream>>>(x, gw, cnt, tok, wtv, tdx, Xb, basep, cntpad);
    gemm1_kernel<<<dim3(FF / 64, TT / 128, NE), 256, 0, stream>>>(Xb, WgT, WuT, tok, basep, cntpad, Hb);
    transpose_d_kernel<<<dim3(16, 11, 8), 256, 0, stream>>>(w_down, WdT);
    gemm2_kernel<<<dim3(DD / 64, TT / 128, NE), 256, 0, stream>>>(Hb, WdT, wtv, tdx, basep, cntpad, out);
}

// Round 7
// 509.440 us; speedup vs baseline: 1.1732x; 1.1732x over previous
//
#include <hip/hip_runtime.h>
#include <stdint.h>

// ---------------------------------------------------------------------------
// Qwen2 MoE sparse block, MI355X/gfx950.  FP32 I/O, bf16 MFMA internally.
// T=2048, D=2048, E=8, F=1408, top-2.  Sparse dispatch (~71 GFLOP vs 283).
// Round 7: revert round-6 regressions (BK=32; Y-buffer + combine, no atomics);
// both GEMMs now m97-structure 128x128 tiles + global_load_lds 16B.
// ---------------------------------------------------------------------------

#define TT 2048
#define DD 2048
#define FF 1408
#define NE 8
#define HROWS 5120          // >= sum of per-expert counts padded to 128 (<=5112)
#define TRASH (2*TT)        // Y trash row for pad entries

typedef float f32x4 __attribute__((ext_vector_type(4)));
typedef short bf16x8 __attribute__((ext_vector_type(8)));

__device__ __forceinline__ unsigned short f2bf(float f) {
    unsigned int x = __float_as_uint(f);
    return (unsigned short)((x + 0x7fffu + ((x >> 16) & 1u)) >> 16);
}
__device__ __forceinline__ float bf2f(unsigned short u) {
    union { unsigned int i; float f; } v; v.i = ((unsigned int)u) << 16; return v.f;
}
__device__ __forceinline__ void gld16(const void* g, void* l) {
    __builtin_amdgcn_global_load_lds((const __attribute__((address_space(1))) void*)g,
                                     (__attribute__((address_space(3))) void*)l, 16, 0, 0);
}

// ---------------------------------------------------------------------------
// Register-blocklet transpose + fp32->bf16 (HBM-bound, ~85 us both).
// ---------------------------------------------------------------------------
__device__ __forceinline__ void treg(const float* __restrict__ src,
                                     unsigned short* __restrict__ dst,
                                     int R, int C, int r0, int c0) {
    const int lane = threadIdx.x & 63, w = threadIdx.x >> 6;
    const int bi = lane >> 3, bj = lane & 7;
    const int sr = r0 + (w & 1) * 64 + bi * 8;
    const int sc = c0 + (w >> 1) * 64 + bj * 8;
    float4 fa[8], fb[8];
#pragma unroll
    for (int k = 0; k < 8; ++k) {
        const float* p = src + (size_t)(sr + k) * C + sc;
        fa[k] = ((const float4*)p)[0];
        fb[k] = ((const float4*)p)[1];
    }
#pragma unroll
    for (int k = 0; k < 8; ++k) {
        uint4 ov; unsigned short* po = (unsigned short*)&ov;
#pragma unroll
        for (int l = 0; l < 8; ++l) {
            float v = (k < 4) ? ((const float*)&fa[l])[k]
                              : ((const float*)&fb[l])[k - 4];
            po[l] = f2bf(v);
        }
        *(uint4*)&dst[(size_t)(sc + k) * R + sr] = ov;
    }
}

__global__ void transpose_gu_kernel(const float* __restrict__ wg,
                                    const float* __restrict__ wu,
                                    unsigned short* __restrict__ WgT,
                                    unsigned short* __restrict__ WuT) {
    const int z = blockIdx.z;
    const float* src; unsigned short* dst;
    if (z < 8) { src = wg + (size_t)z * DD * FF;       dst = WgT + (size_t)z * FF * DD; }
    else       { src = wu + (size_t)(z - 8) * DD * FF; dst = WuT + (size_t)(z - 8) * FF * DD; }
    treg(src, dst, DD, FF, blockIdx.y * 128, blockIdx.x * 128);
}

__global__ void transpose_d_kernel(const float* __restrict__ wd,
                                   unsigned short* __restrict__ WdT) {
    const int z = blockIdx.z;
    treg(wd + (size_t)z * FF * DD, WdT + (size_t)z * DD * FF,
         FF, DD, blockIdx.y * 128, blockIdx.x * 128);
}

// ---------------------------------------------------------------------------
// Router (wave/token, fp32) + X->bf16 emit + fused finalize (last block).
// ---------------------------------------------------------------------------
__global__ void router_kernel(const float* __restrict__ x,
                              const float* __restrict__ gw,
                              int* __restrict__ cnt,        // [NE+1], cnt[NE]=done
                              int* __restrict__ tok,
                              float* __restrict__ wtv,
                              int* __restrict__ dstv,
                              unsigned short* __restrict__ xb,
                              int* __restrict__ basep,
                              int* __restrict__ cntpad) {
    __shared__ int s_last;
    __shared__ int sc[NE], sp[NE];

    const int wv = threadIdx.x >> 6, lane = threadIdx.x & 63;
    const int t = blockIdx.x * 4 + wv;
    float acc[NE];
#pragma unroll
    for (int e = 0; e < NE; ++e) acc[e] = 0.f;
    const float* xr = x + (size_t)t * DD;
    unsigned short* xbr = xb + (size_t)t * DD;
#pragma unroll
    for (int it = 0; it < DD / 256; ++it) {
        const int j = it * 256 + lane * 4;
        float4 xv = *(const float4*)(xr + j);
        short4 o;
        o.x = (short)f2bf(xv.x); o.y = (short)f2bf(xv.y);
        o.z = (short)f2bf(xv.z); o.w = (short)f2bf(xv.w);
        *(short4*)(xbr + j) = o;
#pragma unroll
        for (int e = 0; e < NE; ++e) {
            float4 g = *(const float4*)(gw + e * DD + j);
            acc[e] += xv.x * g.x + xv.y * g.y + xv.z * g.z + xv.w * g.w;
        }
    }
#pragma unroll
    for (int e = 0; e < NE; ++e) {
        float v = acc[e];
        v += __shfl_xor(v, 32); v += __shfl_xor(v, 16); v += __shfl_xor(v, 8);
        v += __shfl_xor(v, 4);  v += __shfl_xor(v, 2);  v += __shfl_xor(v, 1);
        acc[e] = v;
    }
    if (lane == 0) {
        float mx = acc[0];
#pragma unroll
        for (int e = 1; e < NE; ++e) mx = fmaxf(mx, acc[e]);
        float p[NE], s = 0.f;
#pragma unroll
        for (int e = 0; e < NE; ++e) { p[e] = __expf(acc[e] - mx); s += p[e]; }
        int i0 = 0;
#pragma unroll
        for (int e = 1; e < NE; ++e) if (p[e] > p[i0]) i0 = e;
        int i1 = (i0 == 0) ? 1 : 0;
#pragma unroll
        for (int e = 0; e < NE; ++e) if (e != i0 && p[e] > p[i1]) i1 = e;
        float inv = 1.f / s;
        int p0 = atomicAdd(&cnt[i0], 1);
        tok[i0 * TT + p0] = t; wtv[i0 * TT + p0] = p[i0] * inv; dstv[i0 * TT + p0] = 2 * t;
        int p1 = atomicAdd(&cnt[i1], 1);
        tok[i1 * TT + p1] = t; wtv[i1 * TT + p1] = p[i1] * inv; dstv[i1 * TT + p1] = 2 * t + 1;
    }

    __syncthreads();
    if (threadIdx.x == 0) {
        __threadfence();
        int d = atomicAdd(&cnt[NE], 1);
        s_last = (d == (TT / 4) - 1) ? 1 : 0;
    }
    __syncthreads();
    if (s_last) {
        if (threadIdx.x == 0) {
            int b = 0;
            for (int e = 0; e < NE; ++e) {
                int c = atomicAdd(&cnt[e], 0);
                int pd = (c + 127) & ~127;
                basep[e] = b; cntpad[e] = pd; sc[e] = c; sp[e] = pd; b += pd;
            }
        }
        __syncthreads();
        for (int e = 0; e < NE; ++e)
            for (int i = sc[e] + (int)threadIdx.x; i < sp[e]; i += 256) {
                tok[e * TT + i] = 0; wtv[e * TT + i] = 0.f; dstv[e * TT + i] = TRASH;
            }
    }
}

// ---------------------------------------------------------------------------
// GEMM1 fused gate+up+silu*mul.  128M x (128g + 128u)N tile, BK=32, 4 waves
// (2x2 of 64x64), gld16 staging (6 per thread per iter).  fb = FF/128 = 11.
// ---------------------------------------------------------------------------
__launch_bounds__(256, 2)
__global__ void gemm1_kernel(const unsigned short* __restrict__ Xb,
                             const unsigned short* __restrict__ WgT,
                             const unsigned short* __restrict__ WuT,
                             const int* __restrict__ tok,
                             const int* __restrict__ base,
                             const int* __restrict__ cntpad,
                             unsigned short* __restrict__ H) {
    __shared__ unsigned short As[128 * 32];
    __shared__ unsigned short Bg[128 * 32];
    __shared__ unsigned short Bu[128 * 32];
    __shared__ int s_tok[128];

    const int e = blockIdx.z, rb = blockIdx.y, fb = blockIdx.x;
    const int cp = cntpad[e];
    if (rb * 128 >= cp) return;
    const int b0 = base[e];

    const int tid = threadIdx.x;
    if (tid < 128) s_tok[tid] = tok[e * TT + rb * 128 + tid];
    __syncthreads();

    const int w = tid >> 6, lane = tid & 63;
    const int r = lane & 15, q = lane >> 4;
    const int wm = w & 1, wn = w >> 1;

    const int srow = w * 32 + (lane >> 2);   // staged rows: srow, srow+16
    const int koff = (lane & 3) * 8;         // shorts
    const unsigned short* ga0 = Xb + (size_t)s_tok[srow] * DD + koff;
    const unsigned short* ga1 = Xb + (size_t)s_tok[srow + 16] * DD + koff;
    const size_t wb = (size_t)e * FF * DD + (size_t)(fb * 128 + srow) * DD + koff;
    const unsigned short* gg0 = WgT + wb;
    const unsigned short* gg1 = WgT + wb + (size_t)16 * DD;
    const unsigned short* gu0 = WuT + wb;
    const unsigned short* gu1 = WuT + wb + (size_t)16 * DD;
    unsigned short* la0 = As + srow * 32 + koff;   // wave base + lane*16B
    unsigned short* la1 = la0 + 512;
    unsigned short* lg0 = Bg + srow * 32 + koff;
    unsigned short* lg1 = lg0 + 512;
    unsigned short* lu0 = Bu + srow * 32 + koff;
    unsigned short* lu1 = lu0 + 512;

    f32x4 accg[4][4] = {};
    f32x4 accu[4][4] = {};

    for (int kt = 0; kt < DD / 32; ++kt) {
        gld16(ga0, la0); gld16(ga1, la1);
        gld16(gg0, lg0); gld16(gg1, lg1);
        gld16(gu0, lu0); gld16(gu1, lu1);
        ga0 += 32; ga1 += 32; gg0 += 32; gg1 += 32; gu0 += 32; gu1 += 32;
        __syncthreads();
        bf16x8 af[4], gf[4], uf[4];
#pragma unroll
        for (int m = 0; m < 4; ++m)
            af[m] = *(const bf16x8*)&As[(wm * 64 + m * 16 + r) * 32 + q * 8];
#pragma unroll
        for (int n = 0; n < 4; ++n) {
            gf[n] = *(const bf16x8*)&Bg[(wn * 64 + n * 16 + r) * 32 + q * 8];
            uf[n] = *(const bf16x8*)&Bu[(wn * 64 + n * 16 + r) * 32 + q * 8];
        }
#pragma unroll
        for (int m = 0; m < 4; ++m)
#pragma unroll
            for (int n = 0; n < 4; ++n) {
                accg[m][n] = __builtin_amdgcn_mfma_f32_16x16x32_bf16(af[m], gf[n], accg[m][n], 0, 0, 0);
                accu[m][n] = __builtin_amdgcn_mfma_f32_16x16x32_bf16(af[m], uf[n], accu[m][n], 0, 0, 0);
            }
        __syncthreads();
    }

    const size_t hr0 = (size_t)(b0 + rb * 128 + wm * 64);
#pragma unroll
    for (int m = 0; m < 4; ++m)
#pragma unroll
        for (int n = 0; n < 4; ++n)
#pragma unroll
            for (int rr = 0; rr < 4; ++rr) {
                float g = accg[m][n][rr], u = accu[m][n][rr];
                float h = (g / (1.f + __expf(-g))) * u;      // silu(g)*u
                int row = m * 16 + q * 4 + rr;
                int col = fb * 128 + wn * 64 + n * 16 + r;
                H[(hr0 + row) * FF + col] = f2bf(h);
            }
}

// ---------------------------------------------------------------------------
// GEMM2: Y[dst,d] = w * (H_row . WdT[d,:]).  128x128, BK=32, gld16.
// ---------------------------------------------------------------------------
__launch_bounds__(256, 2)
__global__ void gemm2_kernel(const unsigned short* __restrict__ H,
                             const unsigned short* __restrict__ WdT,
                             const float* __restrict__ wtv,
                             const int* __restrict__ dstv,
                             const int* __restrict__ base,
                             const int* __restrict__ cntpad,
                             unsigned short* __restrict__ Y) {
    __shared__ unsigned short As[128 * 32];
    __shared__ unsigned short Bs[128 * 32];
    __shared__ float s_w[128];
    __shared__ int s_d[128];

    const int e = blockIdx.z, rb = blockIdx.y, db = blockIdx.x;   // db 0..15
    const int cp = cntpad[e];
    if (rb * 128 >= cp) return;
    const int b0 = base[e];

    const int tid = threadIdx.x;
    if (tid < 128) {
        int idx = e * TT + rb * 128 + tid;
        s_w[tid] = wtv[idx]; s_d[tid] = dstv[idx];
    }
    __syncthreads();

    const int w = tid >> 6, lane = tid & 63;
    const int r = lane & 15, q = lane >> 4;
    const int wm = w & 1, wn = w >> 1;

    const int srow = w * 32 + (lane >> 2);
    const int koff = (lane & 3) * 8;
    const unsigned short* ga0 = H + (size_t)(b0 + rb * 128 + srow) * FF + koff;
    const unsigned short* ga1 = ga0 + (size_t)16 * FF;
    const unsigned short* gb0 = WdT + (size_t)e * DD * FF + (size_t)(db * 128 + srow) * FF + koff;
    const unsigned short* gb1 = gb0 + (size_t)16 * FF;
    unsigned short* la0 = As + srow * 32 + koff;
    unsigned short* la1 = la0 + 512;
    unsigned short* lb0 = Bs + srow * 32 + koff;
    unsigned short* lb1 = lb0 + 512;

    f32x4 acc[4][4] = {};

    for (int kt = 0; kt < FF / 32; ++kt) {
        gld16(ga0, la0); gld16(ga1, la1);
        gld16(gb0, lb0); gld16(gb1, lb1);
        ga0 += 32; ga1 += 32; gb0 += 32; gb1 += 32;
        __syncthreads();
        bf16x8 af[4], bf[4];
#pragma unroll
        for (int m = 0; m < 4; ++m)
            af[m] = *(const bf16x8*)&As[(wm * 64 + m * 16 + r) * 32 + q * 8];
#pragma unroll
        for (int n = 0; n < 4; ++n)
            bf[n] = *(const bf16x8*)&Bs[(wn * 64 + n * 16 + r) * 32 + q * 8];
#pragma unroll
        for (int m = 0; m < 4; ++m)
#pragma unroll
            for (int n = 0; n < 4; ++n)
                acc[m][n] = __builtin_amdgcn_mfma_f32_16x16x32_bf16(af[m], bf[n], acc[m][n], 0, 0, 0);
        __syncthreads();
    }

#pragma unroll
    for (int m = 0; m < 4; ++m)
#pragma unroll
        for (int n = 0; n < 4; ++n)
#pragma unroll
            for (int rr = 0; rr < 4; ++rr) {
                int row = wm * 64 + m * 16 + q * 4 + rr;
                int col = db * 128 + wn * 64 + n * 16 + r;
                float v = s_w[row] * acc[m][n][rr];
                Y[(size_t)s_d[row] * DD + col] = f2bf(v);
            }
}

// ---------------------------------------------------------------------------
// Combine: out[t,d] = Y[2t,d] + Y[2t+1,d]  -> fp32 out.
// ---------------------------------------------------------------------------
__global__ void combine_kernel(const unsigned short* __restrict__ Y,
                               float* __restrict__ out) {
    const int t = blockIdx.x;
    const int d = threadIdx.x * 8;
    uint4 a = *(const uint4*)(Y + (size_t)(2 * t) * DD + d);
    uint4 b = *(const uint4*)(Y + (size_t)(2 * t + 1) * DD + d);
    const unsigned short* pa = (const unsigned short*)&a;
    const unsigned short* pb = (const unsigned short*)&b;
    float4 o0, o1;
    o0.x = bf2f(pa[0]) + bf2f(pb[0]);  o0.y = bf2f(pa[1]) + bf2f(pb[1]);
    o0.z = bf2f(pa[2]) + bf2f(pb[2]);  o0.w = bf2f(pa[3]) + bf2f(pb[3]);
    o1.x = bf2f(pa[4]) + bf2f(pb[4]);  o1.y = bf2f(pa[5]) + bf2f(pb[5]);
    o1.z = bf2f(pa[6]) + bf2f(pb[6]);  o1.w = bf2f(pa[7]) + bf2f(pb[7]);
    float* op = out + (size_t)t * DD + d;
    ((float4*)op)[0] = o0;
    ((float4*)op)[1] = o1;
}

// ---------------------------------------------------------------------------
extern "C" void kernel_launch(void* const* d_in, const int* in_sizes, int n_in,
                              void* d_out, int out_size, void* d_ws, size_t ws_size,
                              hipStream_t stream) {
    const float* x      = (const float*)d_in[0];
    const float* gw     = (const float*)d_in[1];
    const float* w_gate = (const float*)d_in[2];
    const float* w_up   = (const float*)d_in[3];
    const float* w_down = (const float*)d_in[4];
    float* out = (float*)d_out;

    uint8_t* ws = (uint8_t*)d_ws;
    size_t off = 0;
    auto alloc = [&](size_t bytes) -> void* {
        void* p = ws + off;
        off = (off + bytes + 255) & ~(size_t)255;
        return p;
    };
    int*   cnt    = (int*)  alloc((NE + 1) * 4);
    int*   basep  = (int*)  alloc(NE * 4);
    int*   cntpad = (int*)  alloc(NE * 4);
    int*   tok    = (int*)  alloc((size_t)NE * TT * 4);
    float* wtv    = (float*)alloc((size_t)NE * TT * 4);
    int*   dstv   = (int*)  alloc((size_t)NE * TT * 4);
    unsigned short* Xb  = (unsigned short*)alloc((size_t)TT * DD * 2);
    unsigned short* Hb  = (unsigned short*)alloc((size_t)HROWS * FF * 2);
    unsigned short* Yb  = (unsigned short*)alloc((size_t)(2 * TT + 8) * DD * 2);
    // Reused region: WgT+WuT (bf16) for gemm1, then WdT aliases WgT for gemm2.
    unsigned short* WT  = (unsigned short*)alloc((size_t)2 * NE * FF * DD * 2);
    unsigned short* WgT = WT;
    unsigned short* WuT = WT + (size_t)NE * FF * DD;
    unsigned short* WdT = WT;
    (void)ws_size; (void)in_sizes; (void)n_in; (void)out_size;

    hipMemsetAsync(cnt, 0, (NE + 1) * 4, stream);
    transpose_gu_kernel<<<dim3(11, 16, 16), 256, 0, stream>>>(w_gate, w_up, WgT, WuT);
    router_kernel<<<dim3(TT / 4), 256, 0, stream>>>(x, gw, cnt, tok, wtv, dstv, Xb, basep, cntpad);
    gemm1_kernel<<<dim3(FF / 128, TT / 128, NE), 256, 0, stream>>>(Xb, WgT, WuT, tok, basep, cntpad, Hb);
    transpose_d_kernel<<<dim3(16, 11, 8), 256, 0, stream>>>(w_down, WdT);
    gemm2_kernel<<<dim3(DD / 128, TT / 128, NE), 256, 0, stream>>>(Hb, WdT, wtv, dstv, basep, cntpad, Yb);
    combine_kernel<<<dim3(TT), 256, 0, stream>>>(Yb, out);
}